// Round 12
// baseline (98.643 us; speedup 1.0000x reference)
//
#include <hip/hip_runtime.h>
#include <hip/hip_bf16.h>
#include <stdint.h>

// Problem: B=8, S=2048, D=1024, E=8, CAP=512, TOK=16384.
// Outputs (concat f32): hidden[16384*1024], logits[16384*8], expert_index[16384]

typedef __attribute__((ext_vector_type(8))) short short8;   // 8 x bf16 (4 VGPRs)
typedef __attribute__((ext_vector_type(4))) float f32x4;

#define AS1 __attribute__((address_space(1)))
#define AS3 __attribute__((address_space(3)))

static __device__ __forceinline__ uint32_t f2bf(float f) {
  __hip_bfloat16 h = __float2bfloat16(f);
  return (uint32_t)*reinterpret_cast<unsigned short*>(&h);
}

// resolve capacity-rank g within expert e -> token id, via per-(e,b) segments
static __device__ __forceinline__ int resolve_rid(const int* __restrict__ neb,
                                                  const int* __restrict__ slots,
                                                  int e, int g) {
  int acc = 0;
#pragma unroll
  for (int b = 0; b < 8; ++b) {
    int c = neb[e * 8 + b];
    if (g >= acc && g < acc + c) return slots[e * 4096 + b * 512 + (g - acc)];
    acc += c;
  }
  return slots[e * 4096];  // unreachable for valid g
}

// ------- Kernel 1: FUSED router (blocks 0..4095) + wconv (blocks 4096..4351) -
// wconv rewritten as 256 PANEL blocks: block (e,kt) reads the 32x1024 f32
// k-slab in 4 chunks of 32x256 (coalesced 1KB/row), transposes via padded LDS
// (stride 257 -> conflict-free column reads), writes the 64KB kt-panel
// [n][32] bf16 with perfectly-linear 64B-per-thread stores.
__global__ __launch_bounds__(256) void k_front(
    const float* __restrict__ x, const float* __restrict__ gw,
    const float* __restrict__ w,
    __hip_bfloat16* __restrict__ xb, __hip_bfloat16* __restrict__ wt,
    float* __restrict__ logits, float* __restrict__ tprob, int* __restrict__ texp) {
  __shared__ __align__(16) float gs[32 * 257 + 28];  // 32.9KB; router uses 32KB prefix
  const int tid = threadIdx.x;
  const int bid = blockIdx.x;

  if (bid < 4096) {
    // ---------------- router: logits f32, softmax top-1, x -> bf16 ----------
    {
      const float4* g4 = reinterpret_cast<const float4*>(gw);
      float4* s4 = reinterpret_cast<float4*>(gs);
#pragma unroll
      for (int i = 0; i < 8; ++i) s4[tid + 256 * i] = g4[tid + 256 * i];
    }
    __syncthreads();
    const int wave = tid >> 6, lane = tid & 63;
    const int t = bid * 4 + wave;  // one wave per token
    const float2* x2 = reinterpret_cast<const float2*>(x + (size_t)t * 1024);
    uint32_t* xbu = reinterpret_cast<uint32_t*>(xb + (size_t)t * 1024);
    const float2* g2 = reinterpret_cast<const float2*>(gs);
    float acc[8];
#pragma unroll
    for (int e = 0; e < 8; ++e) acc[e] = 0.f;
#pragma unroll
    for (int kk = 0; kk < 8; ++kk) {
      int p = lane + 64 * kk;  // lane-stride-1 (conflict-free LDS)
      float2 xv = x2[p];
      xbu[p] = f2bf(xv.x) | (f2bf(xv.y) << 16);
#pragma unroll
      for (int e = 0; e < 8; ++e) {
        float2 g = g2[e * 512 + p];
        acc[e] = fmaf(xv.x, g.x, acc[e]);
        acc[e] = fmaf(xv.y, g.y, acc[e]);
      }
    }
#pragma unroll
    for (int d = 1; d < 64; d <<= 1) {
#pragma unroll
      for (int e = 0; e < 8; ++e) acc[e] += __shfl_xor(acc[e], d, 64);
    }
    if (lane == 0) {
      float m = acc[0];
      int idx = 0;
#pragma unroll
      for (int e = 1; e < 8; ++e)
        if (acc[e] > m) { m = acc[e]; idx = e; }  // strict '>' == argmax-first tiebreak
      float s = 0.f;
#pragma unroll
      for (int e = 0; e < 8; ++e) s += expf(acc[e] - m);
      tprob[t] = 1.0f / s;   // softmax prob of the max logit
      texp[t] = idx;
#pragma unroll
      for (int e = 0; e < 8; ++e) logits[(size_t)t * 8 + e] = acc[e];
    }
  } else {
    // ---- wconv panel block: (e,kt) -> wt[e][kt][n][32] bf16, kt = k>>5 ----
    const int bx = bid - 4096;            // 0..255 = 8e * 32kt
    const int e = bx >> 5;
    const int kt = bx & 31;
    const float* ws = w + (size_t)e * 1024 * 1024 + (size_t)kt * 32 * 1024;
    __hip_bfloat16* wd = wt + (size_t)e * 1024 * 1024 + (size_t)kt * 32768;
    float (*tile)[257] = reinterpret_cast<float (*)[257]>(gs);  // [32][257] pad
#pragma unroll
    for (int nc = 0; nc < 4; ++nc) {
      __syncthreads();  // protect previous chunk's readers
      // load 32 rows x 256 cols (float4 coalesced: 2048 float4, 8/thread)
#pragma unroll
      for (int i = 0; i < 8; ++i) {
        int idx = i * 256 + tid;
        int r = idx >> 6, c4 = idx & 63;
        float4 v = *reinterpret_cast<const float4*>(ws + (size_t)r * 1024 + nc * 256 + c4 * 4);
        tile[r][c4 * 4 + 0] = v.x;
        tile[r][c4 * 4 + 1] = v.y;
        tile[r][c4 * 4 + 2] = v.z;
        tile[r][c4 * 4 + 3] = v.w;
      }
      __syncthreads();
      // thread tid owns column n_local = tid: 32 column reads (stride 257,
      // conflict-free), pack to 32 bf16 = 64B, linear coalesced store.
      uint32_t pk[16];
#pragma unroll
      for (int kk = 0; kk < 16; ++kk)
        pk[kk] = f2bf(tile[2 * kk][tid]) | (f2bf(tile[2 * kk + 1][tid]) << 16);
      uint4* dst = reinterpret_cast<uint4*>(wd + (size_t)(nc * 256 + tid) * 32);
#pragma unroll
      for (int q = 0; q < 4; ++q)
        dst[q] = make_uint4(pk[4 * q], pk[4 * q + 1], pk[4 * q + 2], pk[4 * q + 3]);
    }
  }
}

// -------- Kernel 3: per-batch capacity scan + FUSED identity pass-through ----
__global__ __launch_bounds__(256) void k_scan(
    const int* __restrict__ texp, const float* __restrict__ x,
    int* __restrict__ slots, int* __restrict__ neb,
    float* __restrict__ tprob, float* __restrict__ idx_out,
    float* __restrict__ out) {
  const int b = blockIdx.x;  // grid = 8
  const int tid = threadIdx.x;
  __shared__ int te_s[2048];
  __shared__ int dlist[2048];
  __shared__ int ndrop;
  if (tid == 0) ndrop = 0;
#pragma unroll
  for (int i = 0; i < 8; ++i) te_s[tid + 256 * i] = texp[b * 2048 + tid + 256 * i];
  __syncthreads();

  int myte[8], cnt[8];
#pragma unroll
  for (int e = 0; e < 8; ++e) cnt[e] = 0;
#pragma unroll
  for (int j = 0; j < 8; ++j) {  // thread owns 8 consecutive tokens
    int v = te_s[tid * 8 + j];
    myte[j] = v;
#pragma unroll
    for (int e = 0; e < 8; ++e) cnt[e] += (v == e);
  }
  unsigned u0 = (unsigned)cnt[0] | ((unsigned)cnt[1] << 16);
  unsigned u1 = (unsigned)cnt[2] | ((unsigned)cnt[3] << 16);
  unsigned u2 = (unsigned)cnt[4] | ((unsigned)cnt[5] << 16);
  unsigned u3 = (unsigned)cnt[6] | ((unsigned)cnt[7] << 16);
  const int lane = tid & 63, wave = tid >> 6;
#pragma unroll
  for (int d = 1; d < 64; d <<= 1) {  // inclusive scan within wave
    unsigned v0 = __shfl_up(u0, d, 64);
    unsigned v1 = __shfl_up(u1, d, 64);
    unsigned v2 = __shfl_up(u2, d, 64);
    unsigned v3 = __shfl_up(u3, d, 64);
    if (lane >= d) { u0 += v0; u1 += v1; u2 += v2; u3 += v3; }
  }
  __shared__ unsigned wtot[4][4];
  if (lane == 63) { wtot[wave][0] = u0; wtot[wave][1] = u1; wtot[wave][2] = u2; wtot[wave][3] = u3; }
  __syncthreads();
  unsigned a0 = 0, a1 = 0, a2 = 0, a3 = 0, s0 = 0, s1 = 0, s2 = 0, s3 = 0;
#pragma unroll
  for (int w = 0; w < 4; ++w) {
    unsigned q0 = wtot[w][0], q1 = wtot[w][1], q2 = wtot[w][2], q3 = wtot[w][3];
    if (w < wave) { a0 += q0; a1 += q1; a2 += q2; a3 += q3; }
    s0 += q0; s1 += q1; s2 += q2; s3 += q3;
  }
  u0 += a0; u1 += a1; u2 += a2; u3 += a3;  // inclusive over whole block
  int base[8];
  base[0] = (int)(u0 & 0xFFFF) - cnt[0]; base[1] = (int)(u0 >> 16) - cnt[1];
  base[2] = (int)(u1 & 0xFFFF) - cnt[2]; base[3] = (int)(u1 >> 16) - cnt[3];
  base[4] = (int)(u2 & 0xFFFF) - cnt[4]; base[5] = (int)(u2 >> 16) - cnt[5];
  base[6] = (int)(u3 & 0xFFFF) - cnt[6]; base[7] = (int)(u3 >> 16) - cnt[7];
  if (tid == 0) {
    int tt[8] = {(int)(s0 & 0xFFFF), (int)(s0 >> 16), (int)(s1 & 0xFFFF), (int)(s1 >> 16),
                 (int)(s2 & 0xFFFF), (int)(s2 >> 16), (int)(s3 & 0xFFFF), (int)(s3 >> 16)};
#pragma unroll
    for (int e = 0; e < 8; ++e) neb[e * 8 + b] = tt[e] < 512 ? tt[e] : 512;
  }
#pragma unroll
  for (int j = 0; j < 8; ++j) {
    int v = myte[j];
    int rank = 0;
#pragma unroll
    for (int e = 0; e < 8; ++e)
      if (v == e) { base[e] += 1; rank = base[e]; }  // 1-based inclusive rank
    int tok = b * 2048 + tid * 8 + j;
    int kp = rank <= 512;
    idx_out[tok] = kp ? (float)v : 0.0f;  // argmax(all-zero mask)=0 for dropped
    if (kp) slots[v * 4096 + b * 512 + rank - 1] = tok;  // deterministic, no atomics
    else dlist[atomicAdd(&ndrop, 1)] = tok;              // LDS atomic, order-free
  }
  __syncthreads();
  const int nd = ndrop;
  for (int d = 0; d < nd; ++d) {
    int tok = dlist[d];
    float s = tprob[tok];
    const float4* xi = reinterpret_cast<const float4*>(x + (size_t)tok * 1024);
    float4* o = reinterpret_cast<float4*>(out + (size_t)tok * 1024);
    float4 v = xi[tid];
    o[tid] = make_float4(s * v.x, s * v.y, s * v.z, s * v.w);
  }
}

// ---------------- Kernel 4: gathered expert GEMM, 128x128xBK32, 4 blocks/CU --
// R11 kernel, byte-identical (61.7 us, MfmaUtil 21.7%, 0 conflicts, best).
__global__ __launch_bounds__(256, 4) void k_gemm(
    const __hip_bfloat16* __restrict__ xb, const __hip_bfloat16* __restrict__ wt,
    const int* __restrict__ neb, const int* __restrict__ slots,
    const float* __restrict__ tprob, float* __restrict__ out) {
  const int bid = blockIdx.x;               // 0..1023
  const int tile = (bid & 7) * 128 + (bid >> 3);  // XCD x <-> expert x
  const int e = tile >> 7;
  const int local = tile & 127;
  const int rt = local >> 3;                // 128-row chunk (ranks rt*128..)
  const int ct = local & 7;                 // 128-col chunk

  __shared__ __align__(16) char dynls[2][16384];  // 2 bufs x (A 8KB + B 8KB)
  __shared__ int rid_s[128];
  __shared__ float tp_s[128];

  const int tid = threadIdx.x;  // 0..255
  const int wave = tid >> 6, lane = tid & 63;
  const int wm = wave >> 1, wn = wave & 1;  // 2x2 wave grid; 64x64 out per wave
  const int frow = lane & 15, qq = lane >> 4;

  int total_cap = 0;
#pragma unroll
  for (int b = 0; b < 8; ++b) total_cap += neb[e * 8 + b];
  int nvalid = total_cap - rt * 128;
  if (nvalid > 128) nvalid = 128;

  if (nvalid > 0) {
    if (tid < 128) {
      int g = rt * 128 + ((tid < nvalid) ? tid : 0);
      int rid = resolve_rid(neb, slots, e, g);
      rid_s[tid] = rid;
      tp_s[tid] = tprob[rid];
    }
    __syncthreads();

    const __hip_bfloat16* wte = wt + ((size_t)e << 20);
    const __hip_bfloat16* pa[2];
    const __hip_bfloat16* pb[2];
#pragma unroll
    for (int p = 0; p < 2; ++p) {
      int cid = p * 256 + tid;
      int row = cid >> 2, slot = cid & 3;
      int kl = (slot ^ ((row >> 1) & 3)) * 8;
      pa[p] = xb + (size_t)rid_s[row] * 1024 + kl;
      pb[p] = wte + (size_t)ct * 4096 + (size_t)row * 32 + kl;  // in kt-panel 0
    }

#define STAGE(kti, bufi)                                                           \
  do {                                                                             \
    char* d_ = dynls[bufi];                                                        \
    _Pragma("unroll") for (int p = 0; p < 2; ++p)                                  \
      __builtin_amdgcn_global_load_lds((const AS1 uint32_t*)(pa[p] + (kti) * 32),  \
                                       (AS3 uint32_t*)(d_ + (p * 256 + tid) * 16), 16, 0, 0); \
    _Pragma("unroll") for (int p = 0; p < 2; ++p)                                  \
      __builtin_amdgcn_global_load_lds((const AS1 uint32_t*)(pb[p] + (size_t)(kti) * 32768), \
                                       (AS3 uint32_t*)(d_ + 8192 + (p * 256 + tid) * 16), 16, 0, 0); \
  } while (0)

    f32x4 acc[4][4];
#pragma unroll
    for (int i = 0; i < 4; ++i)
#pragma unroll
      for (int j = 0; j < 4; ++j) acc[i][j] = 0.f;

    const int sl = qq ^ ((frow >> 1) & 3);               // read-side swizzle
    const int aoffb = (wm * 64 + frow) * 64 + sl * 16;   // bytes into A [128][32]
    const int boffb = (wn * 64 + frow) * 64 + sl * 16;   // bytes into B [128][32]

#define COMPUTE(bufi)                                                              \
  do {                                                                             \
    const char* Ab = dynls[bufi];                                                  \
    const char* Bb = Ab + 8192;                                                    \
    short8 a[4], b[4];                                                             \
    _Pragma("unroll") for (int mi = 0; mi < 4; ++mi)                               \
        a[mi] = *reinterpret_cast<const short8*>(Ab + aoffb + mi * 1024);          \
    _Pragma("unroll") for (int ni = 0; ni < 4; ++ni)                               \
        b[ni] = *reinterpret_cast<const short8*>(Bb + boffb + ni * 1024);          \
    _Pragma("unroll") for (int mi = 0; mi < 4; ++mi)                               \
        _Pragma("unroll") for (int ni = 0; ni < 4; ++ni)                           \
            acc[mi][ni] = __builtin_amdgcn_mfma_f32_16x16x32_bf16(a[mi], b[ni], acc[mi][ni], 0, 0, 0); \
  } while (0)

    STAGE(0, 0);
    __syncthreads();  // vmcnt(0)+lgkmcnt(0)+barrier: buf0 globally resident
    for (int t = 0; t < 32; ++t) {
      if (t + 1 < 32) STAGE(t + 1, (t + 1) & 1);  // issue next-tile loads FIRST
      COMPUTE(t & 1);
      __syncthreads();  // drains this wave's stage loads + barrier: next buf ready
    }
#undef COMPUTE
#undef STAGE

    // C/D layout: col = lane&15, row = (lane>>4)*4 + j   [m89-verified]
    const int colb = ct * 128 + wn * 64 + frow;
    const int rowb = wm * 64 + qq * 4;
#pragma unroll
    for (int mi = 0; mi < 4; ++mi) {
#pragma unroll
      for (int j = 0; j < 4; ++j) {
        int r = rowb + mi * 16 + j;
        if (r < nvalid) {
          size_t ro = (size_t)rid_s[r] * 1024;
          float sc = tp_s[r];
#pragma unroll
          for (int ni = 0; ni < 4; ++ni)
            out[ro + colb + ni * 16] = sc * acc[mi][ni][j];
        }
      }
    }
  }  // nvalid > 0 (main tile)

  // ---------------- thin overflow phase (ranks >= 2048), LDS-free -------------
  int T2 = 0;
  {
#pragma unroll
    for (int ee = 0; ee < 8; ++ee) {
      int s = 0;
#pragma unroll
      for (int b = 0; b < 8; ++b) s += neb[ee * 8 + b];
      int ov = s - 2048; if (ov < 0) ov = 0;
      T2 += ((ov + 31) >> 5) * 8;
    }
  }
  for (int i = bid; i < T2; i += 1024) {
    // decode i -> (e2, mc, ct2) without runtime-indexed arrays (rule #20)
    int e2 = 0, loc = i, found = 0;
#pragma unroll
    for (int k = 0; k < 8; ++k) {
      int s = 0;
#pragma unroll
      for (int b = 0; b < 8; ++b) s += neb[k * 8 + b];
      int ov = s - 2048; if (ov < 0) ov = 0;
      int sz = ((ov + 31) >> 5) * 8;
      if (!found) {
        if (loc < sz) { e2 = k; found = 1; } else { loc -= sz; }
      }
    }
    int tot2 = 0;
#pragma unroll
    for (int b = 0; b < 8; ++b) tot2 += neb[e2 * 8 + b];
    const int mc = loc >> 3, ct2 = loc & 7;
    int nv = tot2 - 2048 - mc * 32;
    if (nv > 32) nv = 32;

    __syncthreads();  // protect rid_s/tp_s readers of previous phase
    if (tid < 32) {
      int g = 2048 + mc * 32 + ((tid < nv) ? tid : 0);
      int rid = resolve_rid(neb, slots, e2, g);
      rid_s[tid] = rid;
      tp_s[tid] = tprob[rid];
    }
    __syncthreads();

    const __hip_bfloat16* wt2 = wt + ((size_t)e2 << 20);
    const __hip_bfloat16* pa0 = xb + (size_t)rid_s[frow] * 1024 + qq * 8;
    const __hip_bfloat16* pa1 = xb + (size_t)rid_s[16 + frow] * 1024 + qq * 8;
    // K-panel B: row n = ct2*128 + wave*32 + frow; elem = kt*32768 + n*32 + qq*8
    const __hip_bfloat16* pb0 = wt2 + (size_t)(ct2 * 128 + wave * 32 + frow) * 32 + qq * 8;
    const __hip_bfloat16* pb1 = pb0 + 16 * 32;
    f32x4 tc00 = 0.f, tc01 = 0.f, tc10 = 0.f, tc11 = 0.f;
#pragma unroll 4
    for (int kk = 0; kk < 32; ++kk) {
      short8 a0 = *reinterpret_cast<const short8*>(pa0);
      short8 a1 = *reinterpret_cast<const short8*>(pa1);
      short8 b0 = *reinterpret_cast<const short8*>(pb0);
      short8 b1 = *reinterpret_cast<const short8*>(pb1);
      tc00 = __builtin_amdgcn_mfma_f32_16x16x32_bf16(a0, b0, tc00, 0, 0, 0);
      tc01 = __builtin_amdgcn_mfma_f32_16x16x32_bf16(a0, b1, tc01, 0, 0, 0);
      tc10 = __builtin_amdgcn_mfma_f32_16x16x32_bf16(a1, b0, tc10, 0, 0, 0);
      tc11 = __builtin_amdgcn_mfma_f32_16x16x32_bf16(a1, b1, tc11, 0, 0, 0);
      pa0 += 32; pa1 += 32; pb0 += 32768; pb1 += 32768;
    }
    const int colt = ct2 * 128 + wave * 32 + frow;
#pragma unroll
    for (int mi = 0; mi < 2; ++mi) {
#pragma unroll
      for (int j = 0; j < 4; ++j) {
        int r = mi * 16 + qq * 4 + j;
        if (r < nv) {
          float sc = tp_s[r];
          size_t ro = (size_t)rid_s[r] * 1024 + colt;
          out[ro]      = sc * (mi == 0 ? tc00[j] : tc10[j]);
          out[ro + 16] = sc * (mi == 0 ? tc01[j] : tc11[j]);
        }
      }
    }
  }
}

extern "C" void kernel_launch(void* const* d_in, const int* in_sizes, int n_in,
                              void* d_out, int out_size, void* d_ws, size_t ws_size,
                              hipStream_t stream) {
  const float* x = (const float*)d_in[0];    // [8,2048,1024]
  const float* gw = (const float*)d_in[1];   // [8,1024]
  const float* w = (const float*)d_in[2];    // [8,1024,1024]
  float* out = (float*)d_out;
  float* logits = out + (size_t)16384 * 1024;
  float* idx_out = logits + (size_t)16384 * 8;

  // workspace layout (~50.7 MB total)
  char* ws = (char*)d_ws;
  __hip_bfloat16* xb = (__hip_bfloat16*)(ws);              // 33554432 B
  __hip_bfloat16* wt = (__hip_bfloat16*)(ws + 33554432);   // 16777216 B (K-panel)
  float* tprob = (float*)(ws + 50331648);                  // 65536 B
  int* texp   = (int*)(ws + 50397184);                     // 65536 B
  int* slots  = (int*)(ws + 50462720);                     // 131072 B
  int* neb    = (int*)(ws + 50593792);                     // 256 B

  hipLaunchKernelGGL(k_front, dim3(4352), dim3(256), 0, stream, x, gw, w, xb, wt, logits, tprob, texp);
  hipLaunchKernelGGL(k_scan,  dim3(8),    dim3(256), 0, stream, texp, x, slots, neb, tprob, idx_out, out);
  hipLaunchKernelGGL(k_gemm,  dim3(1024), dim3(256), 0, stream, xb, wt, neb, slots, tprob, out);
}

// Round 13
// 90.450 us; speedup vs baseline: 1.0906x; 1.0906x over previous
//
#include <hip/hip_runtime.h>
#include <hip/hip_bf16.h>
#include <stdint.h>

// Problem: B=8, S=2048, D=1024, E=8, CAP=512, TOK=16384.
// Outputs (concat f32): hidden[16384*1024], logits[16384*8], expert_index[16384]

typedef __attribute__((ext_vector_type(8))) short short8;   // 8 x bf16 (4 VGPRs)
typedef __attribute__((ext_vector_type(4))) float f32x4;

#define AS1 __attribute__((address_space(1)))
#define AS3 __attribute__((address_space(3)))

static __device__ __forceinline__ uint32_t f2bf(float f) {
  __hip_bfloat16 h = __float2bfloat16(f);
  return (uint32_t)*reinterpret_cast<unsigned short*>(&h);
}

// resolve capacity-rank g within expert e -> token id, via per-(e,b) segments
static __device__ __forceinline__ int resolve_rid(const int* __restrict__ neb,
                                                  const int* __restrict__ slots,
                                                  int e, int g) {
  int acc = 0;
#pragma unroll
  for (int b = 0; b < 8; ++b) {
    int c = neb[e * 8 + b];
    if (g >= acc && g < acc + c) return slots[e * 4096 + b * 512 + (g - acc)];
    acc += c;
  }
  return slots[e * 4096];  // unreachable for valid g
}

// ------- Kernel 1: FUSED router (blocks 0..1023) + wconv (blocks 1024..9215) -
// Router coarsened 4x: 1024 blocks x 16 tokens (4 tokens per wave, sequential)
// -> 32KB gate staging amortized 4x; x read as float4 (16B/lane sweet spot).
// wconv: PROVEN 32x32 padded-tile transpose (R10/R11), K-panel output
// wt[e][kt][n][32] so every GEMM B-tile is 8KB contiguous.
__global__ __launch_bounds__(256) void k_front(
    const float* __restrict__ x, const float* __restrict__ gw,
    const float* __restrict__ w,
    __hip_bfloat16* __restrict__ xb, __hip_bfloat16* __restrict__ wt,
    float* __restrict__ logits, float* __restrict__ tprob, int* __restrict__ texp) {
  __shared__ __align__(16) float gs[8 * 1024];  // 32 KB (router); wconv reuses prefix
  const int tid = threadIdx.x;
  const int bid = blockIdx.x;

  if (bid < 1024) {
    // ---------------- router: logits f32, softmax top-1, x -> bf16 ----------
    {
      const float4* g4 = reinterpret_cast<const float4*>(gw);
      float4* s4 = reinterpret_cast<float4*>(gs);
#pragma unroll
      for (int i = 0; i < 8; ++i) s4[tid + 256 * i] = g4[tid + 256 * i];
    }
    __syncthreads();
    const int wave = tid >> 6, lane = tid & 63;
    const float4* g4 = reinterpret_cast<const float4*>(gs);  // [e][256] float4
#pragma unroll
    for (int tt = 0; tt < 4; ++tt) {
      const int t = bid * 16 + wave * 4 + tt;  // 4 tokens per wave
      const float4* x4 = reinterpret_cast<const float4*>(x + (size_t)t * 1024);
      uint2* xbu = reinterpret_cast<uint2*>(xb + (size_t)t * 1024);
      float acc[8];
#pragma unroll
      for (int e = 0; e < 8; ++e) acc[e] = 0.f;
#pragma unroll
      for (int kk = 0; kk < 4; ++kk) {
        int p = lane + 64 * kk;  // float4 index, lane-stride-1
        float4 xv = x4[p];
        xbu[p] = make_uint2(f2bf(xv.x) | (f2bf(xv.y) << 16),
                            f2bf(xv.z) | (f2bf(xv.w) << 16));
#pragma unroll
        for (int e = 0; e < 8; ++e) {
          float4 g = g4[e * 256 + p];
          acc[e] = fmaf(xv.x, g.x, acc[e]);
          acc[e] = fmaf(xv.y, g.y, acc[e]);
          acc[e] = fmaf(xv.z, g.z, acc[e]);
          acc[e] = fmaf(xv.w, g.w, acc[e]);
        }
      }
#pragma unroll
      for (int d = 1; d < 64; d <<= 1) {
#pragma unroll
        for (int e = 0; e < 8; ++e) acc[e] += __shfl_xor(acc[e], d, 64);
      }
      if (lane == 0) {
        float m = acc[0];
        int idx = 0;
#pragma unroll
        for (int e = 1; e < 8; ++e)
          if (acc[e] > m) { m = acc[e]; idx = e; }  // strict '>' tiebreak
        float s = 0.f;
#pragma unroll
        for (int e = 0; e < 8; ++e) s += expf(acc[e] - m);
        tprob[t] = 1.0f / s;   // softmax prob of the max logit
        texp[t] = idx;
#pragma unroll
        for (int e = 0; e < 8; ++e) logits[(size_t)t * 8 + e] = acc[e];
      }
    }
  } else {
    // -------- wconv: expert_w [e][k][n] f32 -> Wt K-panel [e][kt][n][32] ----
    const int bx = bid - 1024;             // 8192 = 8e * 32 * 32 tiles of 32x32
    const int e = bx >> 10;
    const int rem = bx & 1023;
    const int k0 = (rem >> 5) << 5;
    const int n0 = (rem & 31) << 5;
    float (*tile)[33] = reinterpret_cast<float (*)[33]>(gs);  // 32x33 pad
    const int c = tid & 31, r0 = tid >> 5;
    const float* ws = w + (size_t)e * 1024 * 1024;
#pragma unroll
    for (int i = 0; i < 4; ++i) {
      int r = r0 + 8 * i;
      tile[r][c] = ws[(size_t)(k0 + r) * 1024 + n0 + c];
    }
    __syncthreads();
    __hip_bfloat16* wd = wt + (size_t)e * 1024 * 1024 + (size_t)(k0 >> 5) * 32768;
#pragma unroll
    for (int i = 0; i < 4; ++i) {
      int r = r0 + 8 * i;  // n within tile
      wd[(size_t)(n0 + r) * 32 + c] = __float2bfloat16(tile[c][r]);
    }
  }
}

// -------- Kernel 3: per-batch capacity scan + FUSED identity pass-through ----
__global__ __launch_bounds__(256) void k_scan(
    const int* __restrict__ texp, const float* __restrict__ x,
    int* __restrict__ slots, int* __restrict__ neb,
    float* __restrict__ tprob, float* __restrict__ idx_out,
    float* __restrict__ out) {
  const int b = blockIdx.x;  // grid = 8
  const int tid = threadIdx.x;
  __shared__ int te_s[2048];
  __shared__ int dlist[2048];
  __shared__ int ndrop;
  if (tid == 0) ndrop = 0;
#pragma unroll
  for (int i = 0; i < 8; ++i) te_s[tid + 256 * i] = texp[b * 2048 + tid + 256 * i];
  __syncthreads();

  int myte[8], cnt[8];
#pragma unroll
  for (int e = 0; e < 8; ++e) cnt[e] = 0;
#pragma unroll
  for (int j = 0; j < 8; ++j) {  // thread owns 8 consecutive tokens
    int v = te_s[tid * 8 + j];
    myte[j] = v;
#pragma unroll
    for (int e = 0; e < 8; ++e) cnt[e] += (v == e);
  }
  unsigned u0 = (unsigned)cnt[0] | ((unsigned)cnt[1] << 16);
  unsigned u1 = (unsigned)cnt[2] | ((unsigned)cnt[3] << 16);
  unsigned u2 = (unsigned)cnt[4] | ((unsigned)cnt[5] << 16);
  unsigned u3 = (unsigned)cnt[6] | ((unsigned)cnt[7] << 16);
  const int lane = tid & 63, wave = tid >> 6;
#pragma unroll
  for (int d = 1; d < 64; d <<= 1) {  // inclusive scan within wave
    unsigned v0 = __shfl_up(u0, d, 64);
    unsigned v1 = __shfl_up(u1, d, 64);
    unsigned v2 = __shfl_up(u2, d, 64);
    unsigned v3 = __shfl_up(u3, d, 64);
    if (lane >= d) { u0 += v0; u1 += v1; u2 += v2; u3 += v3; }
  }
  __shared__ unsigned wtot[4][4];
  if (lane == 63) { wtot[wave][0] = u0; wtot[wave][1] = u1; wtot[wave][2] = u2; wtot[wave][3] = u3; }
  __syncthreads();
  unsigned a0 = 0, a1 = 0, a2 = 0, a3 = 0, s0 = 0, s1 = 0, s2 = 0, s3 = 0;
#pragma unroll
  for (int w = 0; w < 4; ++w) {
    unsigned q0 = wtot[w][0], q1 = wtot[w][1], q2 = wtot[w][2], q3 = wtot[w][3];
    if (w < wave) { a0 += q0; a1 += q1; a2 += q2; a3 += q3; }
    s0 += q0; s1 += q1; s2 += q2; s3 += q3;
  }
  u0 += a0; u1 += a1; u2 += a2; u3 += a3;  // inclusive over whole block
  int base[8];
  base[0] = (int)(u0 & 0xFFFF) - cnt[0]; base[1] = (int)(u0 >> 16) - cnt[1];
  base[2] = (int)(u1 & 0xFFFF) - cnt[2]; base[3] = (int)(u1 >> 16) - cnt[3];
  base[4] = (int)(u2 & 0xFFFF) - cnt[4]; base[5] = (int)(u2 >> 16) - cnt[5];
  base[6] = (int)(u3 & 0xFFFF) - cnt[6]; base[7] = (int)(u3 >> 16) - cnt[7];
  if (tid == 0) {
    int tt[8] = {(int)(s0 & 0xFFFF), (int)(s0 >> 16), (int)(s1 & 0xFFFF), (int)(s1 >> 16),
                 (int)(s2 & 0xFFFF), (int)(s2 >> 16), (int)(s3 & 0xFFFF), (int)(s3 >> 16)};
#pragma unroll
    for (int e = 0; e < 8; ++e) neb[e * 8 + b] = tt[e] < 512 ? tt[e] : 512;
  }
#pragma unroll
  for (int j = 0; j < 8; ++j) {
    int v = myte[j];
    int rank = 0;
#pragma unroll
    for (int e = 0; e < 8; ++e)
      if (v == e) { base[e] += 1; rank = base[e]; }  // 1-based inclusive rank
    int tok = b * 2048 + tid * 8 + j;
    int kp = rank <= 512;
    idx_out[tok] = kp ? (float)v : 0.0f;  // argmax(all-zero mask)=0 for dropped
    if (kp) slots[v * 4096 + b * 512 + rank - 1] = tok;  // deterministic, no atomics
    else dlist[atomicAdd(&ndrop, 1)] = tok;              // LDS atomic, order-free
  }
  __syncthreads();
  const int nd = ndrop;
  for (int d = 0; d < nd; ++d) {
    int tok = dlist[d];
    float s = tprob[tok];
    const float4* xi = reinterpret_cast<const float4*>(x + (size_t)tok * 1024);
    float4* o = reinterpret_cast<float4*>(out + (size_t)tok * 1024);
    float4 v = xi[tid];
    o[tid] = make_float4(s * v.x, s * v.y, s * v.z, s * v.w);
  }
}

// ---------------- Kernel 4: gathered expert GEMM, 128x128xBK32, 4 blocks/CU --
// R11 kernel, byte-identical (61.7 us, MfmaUtil 21.7%, 0 conflicts, best).
__global__ __launch_bounds__(256, 4) void k_gemm(
    const __hip_bfloat16* __restrict__ xb, const __hip_bfloat16* __restrict__ wt,
    const int* __restrict__ neb, const int* __restrict__ slots,
    const float* __restrict__ tprob, float* __restrict__ out) {
  const int bid = blockIdx.x;               // 0..1023
  const int tile = (bid & 7) * 128 + (bid >> 3);  // XCD x <-> expert x
  const int e = tile >> 7;
  const int local = tile & 127;
  const int rt = local >> 3;                // 128-row chunk (ranks rt*128..)
  const int ct = local & 7;                 // 128-col chunk

  __shared__ __align__(16) char dynls[2][16384];  // 2 bufs x (A 8KB + B 8KB)
  __shared__ int rid_s[128];
  __shared__ float tp_s[128];

  const int tid = threadIdx.x;  // 0..255
  const int wave = tid >> 6, lane = tid & 63;
  const int wm = wave >> 1, wn = wave & 1;  // 2x2 wave grid; 64x64 out per wave
  const int frow = lane & 15, qq = lane >> 4;

  int total_cap = 0;
#pragma unroll
  for (int b = 0; b < 8; ++b) total_cap += neb[e * 8 + b];
  int nvalid = total_cap - rt * 128;
  if (nvalid > 128) nvalid = 128;

  if (nvalid > 0) {
    if (tid < 128) {
      int g = rt * 128 + ((tid < nvalid) ? tid : 0);
      int rid = resolve_rid(neb, slots, e, g);
      rid_s[tid] = rid;
      tp_s[tid] = tprob[rid];
    }
    __syncthreads();

    const __hip_bfloat16* wte = wt + ((size_t)e << 20);
    const __hip_bfloat16* pa[2];
    const __hip_bfloat16* pb[2];
#pragma unroll
    for (int p = 0; p < 2; ++p) {
      int cid = p * 256 + tid;
      int row = cid >> 2, slot = cid & 3;
      int kl = (slot ^ ((row >> 1) & 3)) * 8;
      pa[p] = xb + (size_t)rid_s[row] * 1024 + kl;
      pb[p] = wte + (size_t)ct * 4096 + (size_t)row * 32 + kl;  // in kt-panel 0
    }

#define STAGE(kti, bufi)                                                           \
  do {                                                                             \
    char* d_ = dynls[bufi];                                                        \
    _Pragma("unroll") for (int p = 0; p < 2; ++p)                                  \
      __builtin_amdgcn_global_load_lds((const AS1 uint32_t*)(pa[p] + (kti) * 32),  \
                                       (AS3 uint32_t*)(d_ + (p * 256 + tid) * 16), 16, 0, 0); \
    _Pragma("unroll") for (int p = 0; p < 2; ++p)                                  \
      __builtin_amdgcn_global_load_lds((const AS1 uint32_t*)(pb[p] + (size_t)(kti) * 32768), \
                                       (AS3 uint32_t*)(d_ + 8192 + (p * 256 + tid) * 16), 16, 0, 0); \
  } while (0)

    f32x4 acc[4][4];
#pragma unroll
    for (int i = 0; i < 4; ++i)
#pragma unroll
      for (int j = 0; j < 4; ++j) acc[i][j] = 0.f;

    const int sl = qq ^ ((frow >> 1) & 3);               // read-side swizzle
    const int aoffb = (wm * 64 + frow) * 64 + sl * 16;   // bytes into A [128][32]
    const int boffb = (wn * 64 + frow) * 64 + sl * 16;   // bytes into B [128][32]

#define COMPUTE(bufi)                                                              \
  do {                                                                             \
    const char* Ab = dynls[bufi];                                                  \
    const char* Bb = Ab + 8192;                                                    \
    short8 a[4], b[4];                                                             \
    _Pragma("unroll") for (int mi = 0; mi < 4; ++mi)                               \
        a[mi] = *reinterpret_cast<const short8*>(Ab + aoffb + mi * 1024);          \
    _Pragma("unroll") for (int ni = 0; ni < 4; ++ni)                               \
        b[ni] = *reinterpret_cast<const short8*>(Bb + boffb + ni * 1024);          \
    _Pragma("unroll") for (int mi = 0; mi < 4; ++mi)                               \
        _Pragma("unroll") for (int ni = 0; ni < 4; ++ni)                           \
            acc[mi][ni] = __builtin_amdgcn_mfma_f32_16x16x32_bf16(a[mi], b[ni], acc[mi][ni], 0, 0, 0); \
  } while (0)

    STAGE(0, 0);
    __syncthreads();  // vmcnt(0)+lgkmcnt(0)+barrier: buf0 globally resident
    for (int t = 0; t < 32; ++t) {
      if (t + 1 < 32) STAGE(t + 1, (t + 1) & 1);  // issue next-tile loads FIRST
      COMPUTE(t & 1);
      __syncthreads();  // drains this wave's stage loads + barrier: next buf ready
    }
#undef COMPUTE
#undef STAGE

    // C/D layout: col = lane&15, row = (lane>>4)*4 + j   [m89-verified]
    const int colb = ct * 128 + wn * 64 + frow;
    const int rowb = wm * 64 + qq * 4;
#pragma unroll
    for (int mi = 0; mi < 4; ++mi) {
#pragma unroll
      for (int j = 0; j < 4; ++j) {
        int r = rowb + mi * 16 + j;
        if (r < nvalid) {
          size_t ro = (size_t)rid_s[r] * 1024;
          float sc = tp_s[r];
#pragma unroll
          for (int ni = 0; ni < 4; ++ni)
            out[ro + colb + ni * 16] = sc * acc[mi][ni][j];
        }
      }
    }
  }  // nvalid > 0 (main tile)

  // ---------------- thin overflow phase (ranks >= 2048), LDS-free -------------
  int T2 = 0;
  {
#pragma unroll
    for (int ee = 0; ee < 8; ++ee) {
      int s = 0;
#pragma unroll
      for (int b = 0; b < 8; ++b) s += neb[ee * 8 + b];
      int ov = s - 2048; if (ov < 0) ov = 0;
      T2 += ((ov + 31) >> 5) * 8;
    }
  }
  for (int i = bid; i < T2; i += 1024) {
    // decode i -> (e2, mc, ct2) without runtime-indexed arrays (rule #20)
    int e2 = 0, loc = i, found = 0;
#pragma unroll
    for (int k = 0; k < 8; ++k) {
      int s = 0;
#pragma unroll
      for (int b = 0; b < 8; ++b) s += neb[k * 8 + b];
      int ov = s - 2048; if (ov < 0) ov = 0;
      int sz = ((ov + 31) >> 5) * 8;
      if (!found) {
        if (loc < sz) { e2 = k; found = 1; } else { loc -= sz; }
      }
    }
    int tot2 = 0;
#pragma unroll
    for (int b = 0; b < 8; ++b) tot2 += neb[e2 * 8 + b];
    const int mc = loc >> 3, ct2 = loc & 7;
    int nv = tot2 - 2048 - mc * 32;
    if (nv > 32) nv = 32;

    __syncthreads();  // protect rid_s/tp_s readers of previous phase
    if (tid < 32) {
      int g = 2048 + mc * 32 + ((tid < nv) ? tid : 0);
      int rid = resolve_rid(neb, slots, e2, g);
      rid_s[tid] = rid;
      tp_s[tid] = tprob[rid];
    }
    __syncthreads();

    const __hip_bfloat16* wt2 = wt + ((size_t)e2 << 20);
    const __hip_bfloat16* pa0 = xb + (size_t)rid_s[frow] * 1024 + qq * 8;
    const __hip_bfloat16* pa1 = xb + (size_t)rid_s[16 + frow] * 1024 + qq * 8;
    // K-panel B: row n = ct2*128 + wave*32 + frow; elem = kt*32768 + n*32 + qq*8
    const __hip_bfloat16* pb0 = wt2 + (size_t)(ct2 * 128 + wave * 32 + frow) * 32 + qq * 8;
    const __hip_bfloat16* pb1 = pb0 + 16 * 32;
    f32x4 tc00 = 0.f, tc01 = 0.f, tc10 = 0.f, tc11 = 0.f;
#pragma unroll 4
    for (int kk = 0; kk < 32; ++kk) {
      short8 a0 = *reinterpret_cast<const short8*>(pa0);
      short8 a1 = *reinterpret_cast<const short8*>(pa1);
      short8 b0 = *reinterpret_cast<const short8*>(pb0);
      short8 b1 = *reinterpret_cast<const short8*>(pb1);
      tc00 = __builtin_amdgcn_mfma_f32_16x16x32_bf16(a0, b0, tc00, 0, 0, 0);
      tc01 = __builtin_amdgcn_mfma_f32_16x16x32_bf16(a0, b1, tc01, 0, 0, 0);
      tc10 = __builtin_amdgcn_mfma_f32_16x16x32_bf16(a1, b0, tc10, 0, 0, 0);
      tc11 = __builtin_amdgcn_mfma_f32_16x16x32_bf16(a1, b1, tc11, 0, 0, 0);
      pa0 += 32; pa1 += 32; pb0 += 32768; pb1 += 32768;
    }
    const int colt = ct2 * 128 + wave * 32 + frow;
#pragma unroll
    for (int mi = 0; mi < 2; ++mi) {
#pragma unroll
      for (int j = 0; j < 4; ++j) {
        int r = mi * 16 + qq * 4 + j;
        if (r < nv) {
          float sc = tp_s[r];
          size_t ro = (size_t)rid_s[r] * 1024 + colt;
          out[ro]      = sc * (mi == 0 ? tc00[j] : tc10[j]);
          out[ro + 16] = sc * (mi == 0 ? tc01[j] : tc11[j]);
        }
      }
    }
  }
}

extern "C" void kernel_launch(void* const* d_in, const int* in_sizes, int n_in,
                              void* d_out, int out_size, void* d_ws, size_t ws_size,
                              hipStream_t stream) {
  const float* x = (const float*)d_in[0];    // [8,2048,1024]
  const float* gw = (const float*)d_in[1];   // [8,1024]
  const float* w = (const float*)d_in[2];    // [8,1024,1024]
  float* out = (float*)d_out;
  float* logits = out + (size_t)16384 * 1024;
  float* idx_out = logits + (size_t)16384 * 8;

  // workspace layout (~50.7 MB total)
  char* ws = (char*)d_ws;
  __hip_bfloat16* xb = (__hip_bfloat16*)(ws);              // 33554432 B
  __hip_bfloat16* wt = (__hip_bfloat16*)(ws + 33554432);   // 16777216 B (K-panel)
  float* tprob = (float*)(ws + 50331648);                  // 65536 B
  int* texp   = (int*)(ws + 50397184);                     // 65536 B
  int* slots  = (int*)(ws + 50462720);                     // 131072 B
  int* neb    = (int*)(ws + 50593792);                     // 256 B

  hipLaunchKernelGGL(k_front, dim3(9216), dim3(256), 0, stream, x, gw, w, xb, wt, logits, tprob, texp);
  hipLaunchKernelGGL(k_scan,  dim3(8),    dim3(256), 0, stream, texp, x, slots, neb, tprob, idx_out, out);
  hipLaunchKernelGGL(k_gemm,  dim3(1024), dim3(256), 0, stream, xb, wt, neb, slots, tprob, out);
}

// Round 14
// 90.293 us; speedup vs baseline: 1.0925x; 1.0017x over previous
//
#include <hip/hip_runtime.h>
#include <hip/hip_bf16.h>
#include <stdint.h>

// Problem: B=8, S=2048, D=1024, E=8, CAP=512, TOK=16384.
// Outputs (concat f32): hidden[16384*1024], logits[16384*8], expert_index[16384]

typedef __attribute__((ext_vector_type(8))) short short8;   // 8 x bf16 (4 VGPRs)
typedef __attribute__((ext_vector_type(4))) float f32x4;

#define AS1 __attribute__((address_space(1)))
#define AS3 __attribute__((address_space(3)))

static __device__ __forceinline__ uint32_t f2bf(float f) {
  __hip_bfloat16 h = __float2bfloat16(f);
  return (uint32_t)*reinterpret_cast<unsigned short*>(&h);
}

// resolve capacity-rank g within expert e -> token id, via per-(e,b) segments
static __device__ __forceinline__ int resolve_rid(const int* __restrict__ neb,
                                                  const int* __restrict__ slots,
                                                  int e, int g) {
  int acc = 0;
#pragma unroll
  for (int b = 0; b < 8; ++b) {
    int c = neb[e * 8 + b];
    if (g >= acc && g < acc + c) return slots[e * 4096 + b * 512 + (g - acc)];
    acc += c;
  }
  return slots[e * 4096];  // unreachable for valid g
}

// ------- Kernel 1: FUSED router (blocks 0..1023) + wconv (blocks 1024..9215) -
// (R13, unchanged) Router coarsened 4x: 1024 blocks x 16 tokens; float4 x reads.
// wconv: proven 32x32 padded-tile transpose, K-panel output wt[e][kt][n][32].
__global__ __launch_bounds__(256) void k_front(
    const float* __restrict__ x, const float* __restrict__ gw,
    const float* __restrict__ w,
    __hip_bfloat16* __restrict__ xb, __hip_bfloat16* __restrict__ wt,
    float* __restrict__ logits, float* __restrict__ tprob, int* __restrict__ texp) {
  __shared__ __align__(16) float gs[8 * 1024];  // 32 KB (router); wconv reuses prefix
  const int tid = threadIdx.x;
  const int bid = blockIdx.x;

  if (bid < 1024) {
    {
      const float4* g4 = reinterpret_cast<const float4*>(gw);
      float4* s4 = reinterpret_cast<float4*>(gs);
#pragma unroll
      for (int i = 0; i < 8; ++i) s4[tid + 256 * i] = g4[tid + 256 * i];
    }
    __syncthreads();
    const int wave = tid >> 6, lane = tid & 63;
    const float4* g4 = reinterpret_cast<const float4*>(gs);  // [e][256] float4
#pragma unroll
    for (int tt = 0; tt < 4; ++tt) {
      const int t = bid * 16 + wave * 4 + tt;  // 4 tokens per wave
      const float4* x4 = reinterpret_cast<const float4*>(x + (size_t)t * 1024);
      uint2* xbu = reinterpret_cast<uint2*>(xb + (size_t)t * 1024);
      float acc[8];
#pragma unroll
      for (int e = 0; e < 8; ++e) acc[e] = 0.f;
#pragma unroll
      for (int kk = 0; kk < 4; ++kk) {
        int p = lane + 64 * kk;  // float4 index, lane-stride-1
        float4 xv = x4[p];
        xbu[p] = make_uint2(f2bf(xv.x) | (f2bf(xv.y) << 16),
                            f2bf(xv.z) | (f2bf(xv.w) << 16));
#pragma unroll
        for (int e = 0; e < 8; ++e) {
          float4 g = g4[e * 256 + p];
          acc[e] = fmaf(xv.x, g.x, acc[e]);
          acc[e] = fmaf(xv.y, g.y, acc[e]);
          acc[e] = fmaf(xv.z, g.z, acc[e]);
          acc[e] = fmaf(xv.w, g.w, acc[e]);
        }
      }
#pragma unroll
      for (int d = 1; d < 64; d <<= 1) {
#pragma unroll
        for (int e = 0; e < 8; ++e) acc[e] += __shfl_xor(acc[e], d, 64);
      }
      if (lane == 0) {
        float m = acc[0];
        int idx = 0;
#pragma unroll
        for (int e = 1; e < 8; ++e)
          if (acc[e] > m) { m = acc[e]; idx = e; }  // strict '>' tiebreak
        float s = 0.f;
#pragma unroll
        for (int e = 0; e < 8; ++e) s += expf(acc[e] - m);
        tprob[t] = 1.0f / s;   // softmax prob of the max logit
        texp[t] = idx;
#pragma unroll
        for (int e = 0; e < 8; ++e) logits[(size_t)t * 8 + e] = acc[e];
      }
    }
  } else {
    // -------- wconv: expert_w [e][k][n] f32 -> Wt K-panel [e][kt][n][32] ----
    const int bx = bid - 1024;             // 8192 = 8e * 32 * 32 tiles of 32x32
    const int e = bx >> 10;
    const int rem = bx & 1023;
    const int k0 = (rem >> 5) << 5;
    const int n0 = (rem & 31) << 5;
    float (*tile)[33] = reinterpret_cast<float (*)[33]>(gs);  // 32x33 pad
    const int c = tid & 31, r0 = tid >> 5;
    const float* ws = w + (size_t)e * 1024 * 1024;
#pragma unroll
    for (int i = 0; i < 4; ++i) {
      int r = r0 + 8 * i;
      tile[r][c] = ws[(size_t)(k0 + r) * 1024 + n0 + c];
    }
    __syncthreads();
    __hip_bfloat16* wd = wt + (size_t)e * 1024 * 1024 + (size_t)(k0 >> 5) * 32768;
#pragma unroll
    for (int i = 0; i < 4; ++i) {
      int r = r0 + 8 * i;  // n within tile
      wd[(size_t)(n0 + r) * 32 + c] = __float2bfloat16(tile[c][r]);
    }
  }
}

// -------- Kernel 3: per-batch capacity scan + FUSED identity pass-through ----
__global__ __launch_bounds__(256) void k_scan(
    const int* __restrict__ texp, const float* __restrict__ x,
    int* __restrict__ slots, int* __restrict__ neb,
    float* __restrict__ tprob, float* __restrict__ idx_out,
    float* __restrict__ out) {
  const int b = blockIdx.x;  // grid = 8
  const int tid = threadIdx.x;
  __shared__ int te_s[2048];
  __shared__ int dlist[2048];
  __shared__ int ndrop;
  if (tid == 0) ndrop = 0;
#pragma unroll
  for (int i = 0; i < 8; ++i) te_s[tid + 256 * i] = texp[b * 2048 + tid + 256 * i];
  __syncthreads();

  int myte[8], cnt[8];
#pragma unroll
  for (int e = 0; e < 8; ++e) cnt[e] = 0;
#pragma unroll
  for (int j = 0; j < 8; ++j) {  // thread owns 8 consecutive tokens
    int v = te_s[tid * 8 + j];
    myte[j] = v;
#pragma unroll
    for (int e = 0; e < 8; ++e) cnt[e] += (v == e);
  }
  unsigned u0 = (unsigned)cnt[0] | ((unsigned)cnt[1] << 16);
  unsigned u1 = (unsigned)cnt[2] | ((unsigned)cnt[3] << 16);
  unsigned u2 = (unsigned)cnt[4] | ((unsigned)cnt[5] << 16);
  unsigned u3 = (unsigned)cnt[6] | ((unsigned)cnt[7] << 16);
  const int lane = tid & 63, wave = tid >> 6;
#pragma unroll
  for (int d = 1; d < 64; d <<= 1) {  // inclusive scan within wave
    unsigned v0 = __shfl_up(u0, d, 64);
    unsigned v1 = __shfl_up(u1, d, 64);
    unsigned v2 = __shfl_up(u2, d, 64);
    unsigned v3 = __shfl_up(u3, d, 64);
    if (lane >= d) { u0 += v0; u1 += v1; u2 += v2; u3 += v3; }
  }
  __shared__ unsigned wtot[4][4];
  if (lane == 63) { wtot[wave][0] = u0; wtot[wave][1] = u1; wtot[wave][2] = u2; wtot[wave][3] = u3; }
  __syncthreads();
  unsigned a0 = 0, a1 = 0, a2 = 0, a3 = 0, s0 = 0, s1 = 0, s2 = 0, s3 = 0;
#pragma unroll
  for (int w = 0; w < 4; ++w) {
    unsigned q0 = wtot[w][0], q1 = wtot[w][1], q2 = wtot[w][2], q3 = wtot[w][3];
    if (w < wave) { a0 += q0; a1 += q1; a2 += q2; a3 += q3; }
    s0 += q0; s1 += q1; s2 += q2; s3 += q3;
  }
  u0 += a0; u1 += a1; u2 += a2; u3 += a3;  // inclusive over whole block
  int base[8];
  base[0] = (int)(u0 & 0xFFFF) - cnt[0]; base[1] = (int)(u0 >> 16) - cnt[1];
  base[2] = (int)(u1 & 0xFFFF) - cnt[2]; base[3] = (int)(u1 >> 16) - cnt[3];
  base[4] = (int)(u2 & 0xFFFF) - cnt[4]; base[5] = (int)(u2 >> 16) - cnt[5];
  base[6] = (int)(u3 & 0xFFFF) - cnt[6]; base[7] = (int)(u3 >> 16) - cnt[7];
  if (tid == 0) {
    int tt[8] = {(int)(s0 & 0xFFFF), (int)(s0 >> 16), (int)(s1 & 0xFFFF), (int)(s1 >> 16),
                 (int)(s2 & 0xFFFF), (int)(s2 >> 16), (int)(s3 & 0xFFFF), (int)(s3 >> 16)};
#pragma unroll
    for (int e = 0; e < 8; ++e) neb[e * 8 + b] = tt[e] < 512 ? tt[e] : 512;
  }
#pragma unroll
  for (int j = 0; j < 8; ++j) {
    int v = myte[j];
    int rank = 0;
#pragma unroll
    for (int e = 0; e < 8; ++e)
      if (v == e) { base[e] += 1; rank = base[e]; }  // 1-based inclusive rank
    int tok = b * 2048 + tid * 8 + j;
    int kp = rank <= 512;
    idx_out[tok] = kp ? (float)v : 0.0f;  // argmax(all-zero mask)=0 for dropped
    if (kp) slots[v * 4096 + b * 512 + rank - 1] = tok;  // deterministic, no atomics
    else dlist[atomicAdd(&ndrop, 1)] = tok;              // LDS atomic, order-free
  }
  __syncthreads();
  const int nd = ndrop;
  for (int d = 0; d < nd; ++d) {
    int tok = dlist[d];
    float s = tprob[tok];
    const float4* xi = reinterpret_cast<const float4*>(x + (size_t)tok * 1024);
    float4* o = reinterpret_cast<float4*>(out + (size_t)tok * 1024);
    float4 v = xi[tid];
    o[tid] = make_float4(s * v.x, s * v.y, s * v.z, s * v.w);
  }
}

// ---------------- Kernel 4: gathered expert GEMM, 128x128xBK32, 4 blocks/CU --
// R11 geometry + COUNTED vmcnt(4) (the untested cell: counted @ 4 blocks/CU).
// 2-buf; iter t: STAGE(t+1) -> vmcnt(4) [drains t's 4 older loads; t+1's 4
// stay in flight] -> barrier+sched_barrier (global, pinned) -> COMPUTE(t)
// (free compiler lgkmcnt) -> barrier+sched_barrier.
// RAW: vmcnt(4)+barrier guarantee tile t resident for all waves. WAR:
// STAGE(t+1) overwrites buf((t+1)&1) whose last readers (COMPUTE(t-1))
// consumed every ds_read into registers before iter t-1's trailing barrier,
// which all waves crossed before any wave issues STAGE(t+1). No setprio.
__global__ __launch_bounds__(256, 4) void k_gemm(
    const __hip_bfloat16* __restrict__ xb, const __hip_bfloat16* __restrict__ wt,
    const int* __restrict__ neb, const int* __restrict__ slots,
    const float* __restrict__ tprob, float* __restrict__ out) {
  const int bid = blockIdx.x;               // 0..1023
  const int tile = (bid & 7) * 128 + (bid >> 3);  // XCD x <-> expert x
  const int e = tile >> 7;
  const int local = tile & 127;
  const int rt = local >> 3;                // 128-row chunk (ranks rt*128..)
  const int ct = local & 7;                 // 128-col chunk

  __shared__ __align__(16) char dynls[2][16384];  // 2 bufs x (A 8KB + B 8KB)
  __shared__ int rid_s[128];
  __shared__ float tp_s[128];

  const int tid = threadIdx.x;  // 0..255
  const int wave = tid >> 6, lane = tid & 63;
  const int wm = wave >> 1, wn = wave & 1;  // 2x2 wave grid; 64x64 out per wave
  const int frow = lane & 15, qq = lane >> 4;

  int total_cap = 0;
#pragma unroll
  for (int b = 0; b < 8; ++b) total_cap += neb[e * 8 + b];
  int nvalid = total_cap - rt * 128;
  if (nvalid > 128) nvalid = 128;

  if (nvalid > 0) {
    if (tid < 128) {
      int g = rt * 128 + ((tid < nvalid) ? tid : 0);
      int rid = resolve_rid(neb, slots, e, g);
      rid_s[tid] = rid;
      tp_s[tid] = tprob[rid];
    }
    __syncthreads();

    const __hip_bfloat16* wte = wt + ((size_t)e << 20);
    const __hip_bfloat16* pa[2];
    const __hip_bfloat16* pb[2];
#pragma unroll
    for (int p = 0; p < 2; ++p) {
      int cid = p * 256 + tid;
      int row = cid >> 2, slot = cid & 3;
      int kl = (slot ^ ((row >> 1) & 3)) * 8;
      pa[p] = xb + (size_t)rid_s[row] * 1024 + kl;
      pb[p] = wte + (size_t)ct * 4096 + (size_t)row * 32 + kl;  // in kt-panel 0
    }

#define STAGE(kti, bufi)                                                           \
  do {                                                                             \
    char* d_ = dynls[bufi];                                                        \
    _Pragma("unroll") for (int p = 0; p < 2; ++p)                                  \
      __builtin_amdgcn_global_load_lds((const AS1 uint32_t*)(pa[p] + (kti) * 32),  \
                                       (AS3 uint32_t*)(d_ + (p * 256 + tid) * 16), 16, 0, 0); \
    _Pragma("unroll") for (int p = 0; p < 2; ++p)                                  \
      __builtin_amdgcn_global_load_lds((const AS1 uint32_t*)(pb[p] + (size_t)(kti) * 32768), \
                                       (AS3 uint32_t*)(d_ + 8192 + (p * 256 + tid) * 16), 16, 0, 0); \
  } while (0)

    f32x4 acc[4][4];
#pragma unroll
    for (int i = 0; i < 4; ++i)
#pragma unroll
      for (int j = 0; j < 4; ++j) acc[i][j] = 0.f;

    const int sl = qq ^ ((frow >> 1) & 3);               // read-side swizzle
    const int aoffb = (wm * 64 + frow) * 64 + sl * 16;   // bytes into A [128][32]
    const int boffb = (wn * 64 + frow) * 64 + sl * 16;   // bytes into B [128][32]

#define COMPUTE(bufi)                                                              \
  do {                                                                             \
    const char* Ab = dynls[bufi];                                                  \
    const char* Bb = Ab + 8192;                                                    \
    short8 a[4], b[4];                                                             \
    _Pragma("unroll") for (int mi = 0; mi < 4; ++mi)                               \
        a[mi] = *reinterpret_cast<const short8*>(Ab + aoffb + mi * 1024);          \
    _Pragma("unroll") for (int ni = 0; ni < 4; ++ni)                               \
        b[ni] = *reinterpret_cast<const short8*>(Bb + boffb + ni * 1024);          \
    _Pragma("unroll") for (int mi = 0; mi < 4; ++mi)                               \
        _Pragma("unroll") for (int ni = 0; ni < 4; ++ni)                           \
            acc[mi][ni] = __builtin_amdgcn_mfma_f32_16x16x32_bf16(a[mi], b[ni], acc[mi][ni], 0, 0, 0); \
  } while (0)

    STAGE(0, 0);
    for (int t = 0; t < 32; ++t) {
      if (t + 1 < 32) {
        STAGE(t + 1, (t + 1) & 1);  // issue next-tile loads (4/thread in flight)
        asm volatile("s_waitcnt vmcnt(4)" ::: "memory");  // drain tile t's loads
      } else {
        asm volatile("s_waitcnt vmcnt(0)" ::: "memory");
      }
      __builtin_amdgcn_s_barrier();           // tile t globally resident
      __builtin_amdgcn_sched_barrier(0);      // nothing hoists above the barrier
      COMPUTE(t & 1);
      __builtin_amdgcn_s_barrier();           // all waves done reading buf t&1
      __builtin_amdgcn_sched_barrier(0);
    }
#undef COMPUTE
#undef STAGE

    // C/D layout: col = lane&15, row = (lane>>4)*4 + j   [m89-verified]
    const int colb = ct * 128 + wn * 64 + frow;
    const int rowb = wm * 64 + qq * 4;
#pragma unroll
    for (int mi = 0; mi < 4; ++mi) {
#pragma unroll
      for (int j = 0; j < 4; ++j) {
        int r = rowb + mi * 16 + j;
        if (r < nvalid) {
          size_t ro = (size_t)rid_s[r] * 1024;
          float sc = tp_s[r];
#pragma unroll
          for (int ni = 0; ni < 4; ++ni)
            out[ro + colb + ni * 16] = sc * acc[mi][ni][j];
        }
      }
    }
  }  // nvalid > 0 (main tile)

  // ---------------- thin overflow phase (ranks >= 2048), LDS-free -------------
  int T2 = 0;
  {
#pragma unroll
    for (int ee = 0; ee < 8; ++ee) {
      int s = 0;
#pragma unroll
      for (int b = 0; b < 8; ++b) s += neb[ee * 8 + b];
      int ov = s - 2048; if (ov < 0) ov = 0;
      T2 += ((ov + 31) >> 5) * 8;
    }
  }
  for (int i = bid; i < T2; i += 1024) {
    // decode i -> (e2, mc, ct2) without runtime-indexed arrays (rule #20)
    int e2 = 0, loc = i, found = 0;
#pragma unroll
    for (int k = 0; k < 8; ++k) {
      int s = 0;
#pragma unroll
      for (int b = 0; b < 8; ++b) s += neb[k * 8 + b];
      int ov = s - 2048; if (ov < 0) ov = 0;
      int sz = ((ov + 31) >> 5) * 8;
      if (!found) {
        if (loc < sz) { e2 = k; found = 1; } else { loc -= sz; }
      }
    }
    int tot2 = 0;
#pragma unroll
    for (int b = 0; b < 8; ++b) tot2 += neb[e2 * 8 + b];
    const int mc = loc >> 3, ct2 = loc & 7;
    int nv = tot2 - 2048 - mc * 32;
    if (nv > 32) nv = 32;

    __syncthreads();  // protect rid_s/tp_s readers of previous phase
    if (tid < 32) {
      int g = 2048 + mc * 32 + ((tid < nv) ? tid : 0);
      int rid = resolve_rid(neb, slots, e2, g);
      rid_s[tid] = rid;
      tp_s[tid] = tprob[rid];
    }
    __syncthreads();

    const __hip_bfloat16* wt2 = wt + ((size_t)e2 << 20);
    const __hip_bfloat16* pa0 = xb + (size_t)rid_s[frow] * 1024 + qq * 8;
    const __hip_bfloat16* pa1 = xb + (size_t)rid_s[16 + frow] * 1024 + qq * 8;
    // K-panel B: row n = ct2*128 + wave*32 + frow; elem = kt*32768 + n*32 + qq*8
    const __hip_bfloat16* pb0 = wt2 + (size_t)(ct2 * 128 + wave * 32 + frow) * 32 + qq * 8;
    const __hip_bfloat16* pb1 = pb0 + 16 * 32;
    f32x4 tc00 = 0.f, tc01 = 0.f, tc10 = 0.f, tc11 = 0.f;
#pragma unroll 4
    for (int kk = 0; kk < 32; ++kk) {
      short8 a0 = *reinterpret_cast<const short8*>(pa0);
      short8 a1 = *reinterpret_cast<const short8*>(pa1);
      short8 b0 = *reinterpret_cast<const short8*>(pb0);
      short8 b1 = *reinterpret_cast<const short8*>(pb1);
      tc00 = __builtin_amdgcn_mfma_f32_16x16x32_bf16(a0, b0, tc00, 0, 0, 0);
      tc01 = __builtin_amdgcn_mfma_f32_16x16x32_bf16(a0, b1, tc01, 0, 0, 0);
      tc10 = __builtin_amdgcn_mfma_f32_16x16x32_bf16(a1, b0, tc10, 0, 0, 0);
      tc11 = __builtin_amdgcn_mfma_f32_16x16x32_bf16(a1, b1, tc11, 0, 0, 0);
      pa0 += 32; pa1 += 32; pb0 += 32768; pb1 += 32768;
    }
    const int colt = ct2 * 128 + wave * 32 + frow;
#pragma unroll
    for (int mi = 0; mi < 2; ++mi) {
#pragma unroll
      for (int j = 0; j < 4; ++j) {
        int r = mi * 16 + qq * 4 + j;
        if (r < nv) {
          float sc = tp_s[r];
          size_t ro = (size_t)rid_s[r] * 1024 + colt;
          out[ro]      = sc * (mi == 0 ? tc00[j] : tc10[j]);
          out[ro + 16] = sc * (mi == 0 ? tc01[j] : tc11[j]);
        }
      }
    }
  }
}

extern "C" void kernel_launch(void* const* d_in, const int* in_sizes, int n_in,
                              void* d_out, int out_size, void* d_ws, size_t ws_size,
                              hipStream_t stream) {
  const float* x = (const float*)d_in[0];    // [8,2048,1024]
  const float* gw = (const float*)d_in[1];   // [8,1024]
  const float* w = (const float*)d_in[2];    // [8,1024,1024]
  float* out = (float*)d_out;
  float* logits = out + (size_t)16384 * 1024;
  float* idx_out = logits + (size_t)16384 * 8;

  // workspace layout (~50.7 MB total)
  char* ws = (char*)d_ws;
  __hip_bfloat16* xb = (__hip_bfloat16*)(ws);              // 33554432 B
  __hip_bfloat16* wt = (__hip_bfloat16*)(ws + 33554432);   // 16777216 B (K-panel)
  float* tprob = (float*)(ws + 50331648);                  // 65536 B
  int* texp   = (int*)(ws + 50397184);                     // 65536 B
  int* slots  = (int*)(ws + 50462720);                     // 131072 B
  int* neb    = (int*)(ws + 50593792);                     // 256 B

  hipLaunchKernelGGL(k_front, dim3(9216), dim3(256), 0, stream, x, gw, w, xb, wt, logits, tprob, texp);
  hipLaunchKernelGGL(k_scan,  dim3(8),    dim3(256), 0, stream, texp, x, slots, neb, tprob, idx_out, out);
  hipLaunchKernelGGL(k_gemm,  dim3(1024), dim3(256), 0, stream, xb, wt, neb, slots, tprob, out);
}